// Round 3
// baseline (2119.747 us; speedup 1.0000x reference)
//
#include <hip/hip_runtime.h>
#include <math.h>

#define EMBED 1024
#define NHEAD 16
#define HDIM  64
#define MAXPOS 512
#define TOPK  32
#define BB    8
#define TTT   512
#define BT    (BB*TTT)   // 4096 tokens

// ---------------------------------------------------------------------------
// Q/K projection GEMM with fp64 accumulation (discrete top-k path needs
// fp64-accurate scores to match the np reference's ranking decisions).
// out = A(4096 x 1024) @ W(1024 x 1024)^T + bias, scattered to (B,H,T,D).
// Tile 128x64, K-tile 16, 256 threads, 8x4 per-thread double acc.
// Column tile == one head (nb = h).
// ---------------------------------------------------------------------------
__global__ __launch_bounds__(256, 2)
void gemm_qk_f64(const float* __restrict__ A, const float* __restrict__ W,
                 const float* __restrict__ bias, float* __restrict__ out)
{
    __shared__ float As[16][132];
    __shared__ float Bs[16][68];
    const int t  = threadIdx.x;
    const int mb = blockIdx.x;   // 0..31  rows mb*128
    const int nb = blockIdx.y;   // 0..15  cols nb*64  (== head)
    const int tr = t >> 4, tc = t & 15;

    double acc[8][4] = {};

    for (int kt = 0; kt < 1024; kt += 16) {
        #pragma unroll
        for (int i = 0; i < 2; i++) {
            int L   = t + i * 256;
            int row = L >> 2;
            int cg  = (L & 3) * 4;
            float4 a4 = *(const float4*)&A[(size_t)(mb*128 + row)*1024 + kt + cg];
            As[cg+0][row] = a4.x; As[cg+1][row] = a4.y;
            As[cg+2][row] = a4.z; As[cg+3][row] = a4.w;
        }
        {
            int row = t >> 2, cg = (t & 3) * 4;
            float4 b4 = *(const float4*)&W[(size_t)(nb*64 + row)*1024 + kt + cg];
            Bs[cg+0][row] = b4.x; Bs[cg+1][row] = b4.y;
            Bs[cg+2][row] = b4.z; Bs[cg+3][row] = b4.w;
        }
        __syncthreads();
        #pragma unroll
        for (int kk = 0; kk < 16; kk++) {
            float a[8], bv[4];
            *(float4*)&a[0]  = *(const float4*)&As[kk][tr*8];
            *(float4*)&a[4]  = *(const float4*)&As[kk][tr*8+4];
            *(float4*)&bv[0] = *(const float4*)&Bs[kk][tc*4];
            double bd[4] = {(double)bv[0], (double)bv[1], (double)bv[2], (double)bv[3]};
            #pragma unroll
            for (int i = 0; i < 8; i++) {
                double ad = (double)a[i];
                #pragma unroll
                for (int j = 0; j < 4; j++)
                    acc[i][j] = fma(ad, bd[j], acc[i][j]);
            }
        }
        __syncthreads();
    }

    // epilogue: + bias (fp64), round once, scatter to (B,H,T,D)
    #pragma unroll
    for (int i = 0; i < 8; i++) {
        int token = mb*128 + tr*8 + i;
        int b  = token >> 9, tt = token & 511;
        int c0 = nb*64 + tc*4;
        float4 v;
        v.x = (float)(acc[i][0] + (double)bias[c0+0]);
        v.y = (float)(acc[i][1] + (double)bias[c0+1]);
        v.z = (float)(acc[i][2] + (double)bias[c0+2]);
        v.w = (float)(acc[i][3] + (double)bias[c0+3]);
        *(float4*)&out[(((size_t)b*NHEAD + nb)*TTT + tt)*HDIM + tc*4] = v;
    }
}

// ---------------------------------------------------------------------------
// fp32 GEMM (NT) for V projection (scatter=1) and O projection (scatter=0).
// Continuous path: fp32 noise is invisible after bf16-rounded comparison.
// ---------------------------------------------------------------------------
__global__ __launch_bounds__(256, 2)
void gemm_nt(const float* __restrict__ A, const float* __restrict__ W,
             const float* __restrict__ bias, float* __restrict__ out,
             int scatter)
{
    __shared__ float As[16][132];
    __shared__ float Bs[16][132];
    const int t  = threadIdx.x;
    const int mb = blockIdx.x;   // 0..31
    const int nb = blockIdx.y;   // 0..7
    const int tr = t >> 4, tc = t & 15;

    float acc[8][8] = {};

    for (int kt = 0; kt < 1024; kt += 16) {
        #pragma unroll
        for (int i = 0; i < 2; i++) {
            int L   = t + i * 256;
            int row = L >> 2;
            int cg  = (L & 3) * 4;
            float4 a4 = *(const float4*)&A[(size_t)(mb*128 + row)*1024 + kt + cg];
            As[cg+0][row] = a4.x; As[cg+1][row] = a4.y;
            As[cg+2][row] = a4.z; As[cg+3][row] = a4.w;
            float4 b4 = *(const float4*)&W[(size_t)(nb*128 + row)*1024 + kt + cg];
            Bs[cg+0][row] = b4.x; Bs[cg+1][row] = b4.y;
            Bs[cg+2][row] = b4.z; Bs[cg+3][row] = b4.w;
        }
        __syncthreads();
        #pragma unroll
        for (int kk = 0; kk < 16; kk++) {
            float a[8], bv[8];
            *(float4*)&a[0]  = *(const float4*)&As[kk][tr*8];
            *(float4*)&a[4]  = *(const float4*)&As[kk][tr*8+4];
            *(float4*)&bv[0] = *(const float4*)&Bs[kk][tc*8];
            *(float4*)&bv[4] = *(const float4*)&Bs[kk][tc*8+4];
            #pragma unroll
            for (int i = 0; i < 8; i++)
                #pragma unroll
                for (int j = 0; j < 8; j++)
                    acc[i][j] = fmaf(a[i], bv[j], acc[i][j]);
        }
        __syncthreads();
    }

    if (scatter) {
        #pragma unroll
        for (int i = 0; i < 8; i++) {
            int token = mb*128 + tr*8 + i;
            int b  = token >> 9, tt = token & 511;
            #pragma unroll
            for (int jg = 0; jg < 2; jg++) {
                int c = nb*128 + tc*8 + jg*4;
                int h = c >> 6, d = c & 63;
                float4 v;
                v.x = acc[i][jg*4+0] + bias[c+0];
                v.y = acc[i][jg*4+1] + bias[c+1];
                v.z = acc[i][jg*4+2] + bias[c+2];
                v.w = acc[i][jg*4+3] + bias[c+3];
                *(float4*)&out[(((size_t)b*NHEAD + h)*TTT + tt)*HDIM + d] = v;
            }
        }
    } else {
        #pragma unroll
        for (int i = 0; i < 8; i++) {
            int token = mb*128 + tr*8 + i;
            #pragma unroll
            for (int jg = 0; jg < 2; jg++) {
                int c = nb*128 + tc*8 + jg*4;
                float4 v;
                v.x = acc[i][jg*4+0] + bias[c+0];
                v.y = acc[i][jg*4+1] + bias[c+1];
                v.z = acc[i][jg*4+2] + bias[c+2];
                v.w = acc[i][jg*4+3] + bias[c+3];
                *(float4*)&out[(size_t)token*1024 + c] = v;
            }
        }
    }
}

// ---------------------------------------------------------------------------
// Attention core. One block = one (b,h) x 32 query rows.
// Scores computed with fp64 accumulation (+ bias in fp64, single rounding to
// fp32) so the top-32 ranking matches the fp64 np reference. Exact top-32
// threshold via repeated wave-max extraction; softmax gate/sum folded into
// the output scale; PV in fp32 from LDS.
// ---------------------------------------------------------------------------
__global__ __launch_bounds__(256, 1)
void attn_kernel(const float* __restrict__ qb, const float* __restrict__ kb,
                 const float* __restrict__ vb, const float* __restrict__ gates,
                 const float* __restrict__ relb, float* __restrict__ aout)
{
    __shared__ float s[32][512];                       // 64 KB scores/weights
    __shared__ union { float kT[64][132]; float v[128][68]; } u;  // ~34 KB
    __shared__ float qs[32][64];                       // 8 KB
    __shared__ float rowscale[32];

    const int t    = threadIdx.x;
    const int lane = t & 63, wv = t >> 6;
    const int ty   = t >> 5, tx = t & 31;
    const int qt   = blockIdx.x;       // 0..15
    const int bh   = blockIdx.y;       // 0..127
    const int h    = bh & 15, b = bh >> 4;
    const int qrow_g = qt * 32;

    const float* qbase = qb + ((size_t)bh*TTT + qrow_g)*HDIM;
    const float* kbase = kb + (size_t)bh*TTT*HDIM;
    const float* vbase = vb + (size_t)bh*TTT*HDIM;

    // ---- load Q tile (32x64) ----
    for (int L = t; L < 512; L += 256) {
        int row = L >> 4, cg = (L & 15) * 4;
        *(float4*)&qs[row][cg] = *(const float4*)&qbase[(size_t)row*HDIM + cg];
    }

    // ---- scores: 4 K-tiles of 128 cols, fp64 accumulation ----
    for (int ktile = 0; ktile < 4; ktile++) {
        __syncthreads();
        for (int L = t; L < 2048; L += 256) {          // 128 cols x 16 float4
            int col = L >> 4, dg = (L & 15) * 4;
            float4 kv = *(const float4*)&kbase[(size_t)(ktile*128 + col)*HDIM + dg];
            u.kT[dg+0][col] = kv.x; u.kT[dg+1][col] = kv.y;
            u.kT[dg+2][col] = kv.z; u.kT[dg+3][col] = kv.w;
        }
        __syncthreads();
        double acc[4][4] = {};
        #pragma unroll 4
        for (int d = 0; d < 64; d++) {
            float4 kv = *(const float4*)&u.kT[d][tx*4];
            double k0 = (double)kv.x, k1 = (double)kv.y;
            double k2 = (double)kv.z, k3 = (double)kv.w;
            #pragma unroll
            for (int i = 0; i < 4; i++) {
                double qv = (double)qs[ty*4+i][d];
                acc[i][0] = fma(qv, k0, acc[i][0]);
                acc[i][1] = fma(qv, k1, acc[i][1]);
                acc[i][2] = fma(qv, k2, acc[i][2]);
                acc[i][3] = fma(qv, k3, acc[i][3]);
            }
        }
        #pragma unroll
        for (int i = 0; i < 4; i++) {
            int r = ty*4 + i, rg = qrow_g + r;
            #pragma unroll
            for (int j = 0; j < 4; j++) {
                int c = ktile*128 + tx*4 + j;
                s[r][c] = (float)(acc[i][j]*0.125 +
                                  (double)relb[(size_t)(c - rg + 511)*NHEAD + h]);
            }
        }
    }
    __syncthreads();

    // ---- top-32 threshold + softmax weights, per row (wave wv owns 8 rows) ----
    const float gate = gates[h];
    for (int rr = 0; rr < 8; rr++) {
        int row = wv*8 + rr;
        float val[8];
        #pragma unroll
        for (int j = 0; j < 8; j++) val[j] = s[row][lane + 64*j];
        float rowmax = 0.f, thresh = 0.f;
        #pragma unroll 1
        for (int it = 0; it < TOPK; it++) {
            float lm = val[0];
            #pragma unroll
            for (int j = 1; j < 8; j++) lm = fmaxf(lm, val[j]);
            float m = lm;
            #pragma unroll
            for (int off = 32; off >= 1; off >>= 1)
                m = fmaxf(m, __shfl_xor(m, off));
            if (it == 0) rowmax = m;
            thresh = m;
            unsigned long long ball = __ballot(lm == m);
            int first = __ffsll(ball) - 1;
            if (lane == first) {           // zap exactly one instance of m
                bool done = false;
                #pragma unroll
                for (int j = 0; j < 8; j++)
                    if (!done && val[j] == m) { val[j] = -__builtin_inff(); done = true; }
            }
        }
        float sum = 0.f;
        #pragma unroll
        for (int j = 0; j < 8; j++) {
            float sv = s[row][lane + 64*j];
            float w  = (sv >= thresh) ? __expf(sv - rowmax) : 0.f;
            s[row][lane + 64*j] = w;
            sum += w;
        }
        #pragma unroll
        for (int off = 32; off >= 1; off >>= 1)
            sum += __shfl_xor(sum, off);
        if (lane == 0) rowscale[row] = gate / sum;
    }
    __syncthreads();

    // ---- PV: 4 V-tiles of 128 rows ----
    float oacc[4][2] = {};
    for (int vt = 0; vt < 4; vt++) {
        __syncthreads();
        for (int L = t; L < 2048; L += 256) {
            int row = L >> 4, cg = (L & 15) * 4;
            *(float4*)&u.v[row][cg] =
                *(const float4*)&vbase[(size_t)(vt*128 + row)*HDIM + cg];
        }
        __syncthreads();
        #pragma unroll 4
        for (int k = 0; k < 128; k++) {
            float2 vv = *(const float2*)&u.v[k][tx*2];
            #pragma unroll
            for (int i = 0; i < 4; i++) {
                float w = s[ty*4+i][vt*128 + k];
                oacc[i][0] = fmaf(w, vv.x, oacc[i][0]);
                oacc[i][1] = fmaf(w, vv.y, oacc[i][1]);
            }
        }
    }

    // ---- scale by gate/sum and store to (B,T,C) ----
    #pragma unroll
    for (int i = 0; i < 4; i++) {
        int r = ty*4 + i;
        float sc = rowscale[r];
        float2 o;
        o.x = oacc[i][0] * sc;
        o.y = oacc[i][1] * sc;
        *(float2*)&aout[((size_t)(b*TTT + qrow_g + r))*EMBED + h*HDIM + tx*2] = o;
    }
}

// ---------------------------------------------------------------------------
extern "C" void kernel_launch(void* const* d_in, const int* in_sizes, int n_in,
                              void* d_out, int out_size, void* d_ws, size_t ws_size,
                              hipStream_t stream) {
    const float* x     = (const float*)d_in[0];
    const float* Wq    = (const float*)d_in[1];
    const float* bq    = (const float*)d_in[2];
    const float* Wk    = (const float*)d_in[3];
    const float* bk    = (const float*)d_in[4];
    const float* Wv    = (const float*)d_in[5];
    const float* bv    = (const float*)d_in[6];
    const float* Wo    = (const float*)d_in[7];
    const float* bo    = (const float*)d_in[8];
    const float* gates = (const float*)d_in[9];
    const float* relb  = (const float*)d_in[10];
    float* out = (float*)d_out;

    const size_t SZ = (size_t)BT * EMBED;   // 4,194,304 floats
    float* qb = (float*)d_ws;
    float* kb = qb + SZ;
    float* vb = kb + SZ;
    float* ab = vb + SZ;

    dim3 blk(256);
    gemm_qk_f64<<<dim3(32,16), blk, 0, stream>>>(x, Wq, bq, qb);
    gemm_qk_f64<<<dim3(32,16), blk, 0, stream>>>(x, Wk, bk, kb);
    gemm_nt<<<dim3(32,8), blk, 0, stream>>>(x, Wv, bv, vb, 1);
    attn_kernel<<<dim3(16,128), blk, 0, stream>>>(qb, kb, vb, gates, relb, ab);
    gemm_nt<<<dim3(32,8), blk, 0, stream>>>(ab, Wo, bo, out, 0);
}

// Round 4
// 1269.806 us; speedup vs baseline: 1.6693x; 1.6693x over previous
//
#include <hip/hip_runtime.h>
#include <math.h>

#define EMBED 1024
#define NHEAD 16
#define HDIM  64
#define MAXPOS 512
#define TOPK  32
#define BB    8
#define TTT   512
#define BT    (BB*TTT)   // 4096 tokens

// ---------------------------------------------------------------------------
// Q/K projection GEMM with fp64 accumulation (discrete top-k path needs
// fp64-accurate scores to match the np reference's ranking decisions).
// out = A(4096 x 1024) @ W(1024 x 1024)^T + bias, scattered to (B,H,T,D).
// ---------------------------------------------------------------------------
__global__ __launch_bounds__(256, 2)
void gemm_qk_f64(const float* __restrict__ A, const float* __restrict__ W,
                 const float* __restrict__ bias, float* __restrict__ out)
{
    __shared__ float As[16][132];
    __shared__ float Bs[16][68];
    const int t  = threadIdx.x;
    const int mb = blockIdx.x;   // 0..31  rows mb*128
    const int nb = blockIdx.y;   // 0..15  cols nb*64  (== head)
    const int tr = t >> 4, tc = t & 15;

    double acc[8][4] = {};

    for (int kt = 0; kt < 1024; kt += 16) {
        #pragma unroll
        for (int i = 0; i < 2; i++) {
            int L   = t + i * 256;
            int row = L >> 2;
            int cg  = (L & 3) * 4;
            float4 a4 = *(const float4*)&A[(size_t)(mb*128 + row)*1024 + kt + cg];
            As[cg+0][row] = a4.x; As[cg+1][row] = a4.y;
            As[cg+2][row] = a4.z; As[cg+3][row] = a4.w;
        }
        {
            int row = t >> 2, cg = (t & 3) * 4;
            float4 b4 = *(const float4*)&W[(size_t)(nb*64 + row)*1024 + kt + cg];
            Bs[cg+0][row] = b4.x; Bs[cg+1][row] = b4.y;
            Bs[cg+2][row] = b4.z; Bs[cg+3][row] = b4.w;
        }
        __syncthreads();
        #pragma unroll
        for (int kk = 0; kk < 16; kk++) {
            float a[8], bv[4];
            *(float4*)&a[0]  = *(const float4*)&As[kk][tr*8];
            *(float4*)&a[4]  = *(const float4*)&As[kk][tr*8+4];
            *(float4*)&bv[0] = *(const float4*)&Bs[kk][tc*4];
            double bd[4] = {(double)bv[0], (double)bv[1], (double)bv[2], (double)bv[3]};
            #pragma unroll
            for (int i = 0; i < 8; i++) {
                double ad = (double)a[i];
                #pragma unroll
                for (int j = 0; j < 4; j++)
                    acc[i][j] = fma(ad, bd[j], acc[i][j]);
            }
        }
        __syncthreads();
    }

    #pragma unroll
    for (int i = 0; i < 8; i++) {
        int token = mb*128 + tr*8 + i;
        int b  = token >> 9, tt = token & 511;
        int c0 = nb*64 + tc*4;
        float4 v;
        v.x = (float)(acc[i][0] + (double)bias[c0+0]);
        v.y = (float)(acc[i][1] + (double)bias[c0+1]);
        v.z = (float)(acc[i][2] + (double)bias[c0+2]);
        v.w = (float)(acc[i][3] + (double)bias[c0+3]);
        *(float4*)&out[(((size_t)b*NHEAD + nb)*TTT + tt)*HDIM + tc*4] = v;
    }
}

// ---------------------------------------------------------------------------
// fp32 GEMM (NT) for V projection (scatter=1) and O projection (scatter=0).
// ---------------------------------------------------------------------------
__global__ __launch_bounds__(256, 2)
void gemm_nt(const float* __restrict__ A, const float* __restrict__ W,
             const float* __restrict__ bias, float* __restrict__ out,
             int scatter)
{
    __shared__ float As[16][132];
    __shared__ float Bs[16][132];
    const int t  = threadIdx.x;
    const int mb = blockIdx.x;
    const int nb = blockIdx.y;
    const int tr = t >> 4, tc = t & 15;

    float acc[8][8] = {};

    for (int kt = 0; kt < 1024; kt += 16) {
        #pragma unroll
        for (int i = 0; i < 2; i++) {
            int L   = t + i * 256;
            int row = L >> 2;
            int cg  = (L & 3) * 4;
            float4 a4 = *(const float4*)&A[(size_t)(mb*128 + row)*1024 + kt + cg];
            As[cg+0][row] = a4.x; As[cg+1][row] = a4.y;
            As[cg+2][row] = a4.z; As[cg+3][row] = a4.w;
            float4 b4 = *(const float4*)&W[(size_t)(nb*128 + row)*1024 + kt + cg];
            Bs[cg+0][row] = b4.x; Bs[cg+1][row] = b4.y;
            Bs[cg+2][row] = b4.z; Bs[cg+3][row] = b4.w;
        }
        __syncthreads();
        #pragma unroll
        for (int kk = 0; kk < 16; kk++) {
            float a[8], bv[8];
            *(float4*)&a[0]  = *(const float4*)&As[kk][tr*8];
            *(float4*)&a[4]  = *(const float4*)&As[kk][tr*8+4];
            *(float4*)&bv[0] = *(const float4*)&Bs[kk][tc*8];
            *(float4*)&bv[4] = *(const float4*)&Bs[kk][tc*8+4];
            #pragma unroll
            for (int i = 0; i < 8; i++)
                #pragma unroll
                for (int j = 0; j < 8; j++)
                    acc[i][j] = fmaf(a[i], bv[j], acc[i][j]);
        }
        __syncthreads();
    }

    if (scatter) {
        #pragma unroll
        for (int i = 0; i < 8; i++) {
            int token = mb*128 + tr*8 + i;
            int b  = token >> 9, tt = token & 511;
            #pragma unroll
            for (int jg = 0; jg < 2; jg++) {
                int c = nb*128 + tc*8 + jg*4;
                int h = c >> 6, d = c & 63;
                float4 v;
                v.x = acc[i][jg*4+0] + bias[c+0];
                v.y = acc[i][jg*4+1] + bias[c+1];
                v.z = acc[i][jg*4+2] + bias[c+2];
                v.w = acc[i][jg*4+3] + bias[c+3];
                *(float4*)&out[(((size_t)b*NHEAD + h)*TTT + tt)*HDIM + d] = v;
            }
        }
    } else {
        #pragma unroll
        for (int i = 0; i < 8; i++) {
            int token = mb*128 + tr*8 + i;
            #pragma unroll
            for (int jg = 0; jg < 2; jg++) {
                int c = nb*128 + tc*8 + jg*4;
                float4 v;
                v.x = acc[i][jg*4+0] + bias[c+0];
                v.y = acc[i][jg*4+1] + bias[c+1];
                v.z = acc[i][jg*4+2] + bias[c+2];
                v.w = acc[i][jg*4+3] + bias[c+3];
                *(float4*)&out[(size_t)token*1024 + c] = v;
            }
        }
    }
}

// ---------------------------------------------------------------------------
// Attention core, restructured for occupancy + register-resident scores.
// Block = 512 threads (8 waves), one (b,h) x 32 q-rows; wave owns 4 rows.
// Lane owns score cols {lane + 64j, j=0..7} -> sc[4][8] in registers.
// fp64 dot (d ascending, bit-identical to the passing round), reg top-k with
// 4-row ILP interleave, sparse compacted PV (identical fp32 sum: skipped
// entries contributed exactly +0.0 in the dense version).
// LDS ~59 KB -> 2 blocks/CU (16 waves/CU vs 4 before).
// ---------------------------------------------------------------------------
__global__ __launch_bounds__(512, 4)
void attn_kernel(const float* __restrict__ qb, const float* __restrict__ kb,
                 const float* __restrict__ vb, const float* __restrict__ gates,
                 const float* __restrict__ relb, float* __restrict__ aout)
{
    __shared__ double qd[32][64];                       // 16 KB (broadcast reads)
    __shared__ union {
        float ks[128][68];                              // 34.8 KB  K-tile [col][d]
        struct { float w[32][64]; unsigned short c[32][64]; } sp;  // 12 KB
    } u;

    const int t    = threadIdx.x;
    const int lane = t & 63, wv = t >> 6;               // 8 waves
    const int qt   = blockIdx.x;        // 0..15
    const int bh   = blockIdx.y;        // 0..127
    const int h    = bh & 15, b = bh >> 4;
    const int qrow_g = qt * 32;
    const int r0   = wv * 4;            // this wave's 4 block-local rows

    const float* qbase = qb + ((size_t)bh*TTT + qrow_g)*HDIM;
    const float* kbase = kb + (size_t)bh*TTT*HDIM;
    const float* vbase = vb + (size_t)bh*TTT*HDIM;

    // ---- load Q tile (32x64) and convert to fp64 in LDS ----
    {
        int row = t >> 4, cg = (t & 15) * 4;
        float4 a4 = *(const float4*)&qbase[(size_t)row*HDIM + cg];
        double2 d0 = { (double)a4.x, (double)a4.y };
        double2 d1 = { (double)a4.z, (double)a4.w };
        *(double2*)&qd[row][cg]   = d0;
        *(double2*)&qd[row][cg+2] = d1;
    }

    float sc[4][8];                     // scores: sc[i][j] = S[r0+i][lane+64j]

    // ---- scores: 4 K-tiles of 128 cols, fp64 accumulation, d ascending ----
    #pragma unroll
    for (int ktile = 0; ktile < 4; ktile++) {
        __syncthreads();                // protects u.ks (and qd on first iter)
        #pragma unroll
        for (int i = 0; i < 4; i++) {   // stage K tile as [col][d]
            int L   = t + i * 512;
            int col = L >> 4, dg = (L & 15) * 4;
            *(float4*)&u.ks[col][dg] =
                *(const float4*)&kbase[(size_t)(ktile*128 + col)*HDIM + dg];
        }
        __syncthreads();

        double acc[4][2] = {};
        #pragma unroll 2
        for (int d = 0; d < 64; d += 4) {
            float4 k0 = *(const float4*)&u.ks[lane][d];
            float4 k1 = *(const float4*)&u.ks[lane+64][d];
            double k0d[4] = {(double)k0.x,(double)k0.y,(double)k0.z,(double)k0.w};
            double k1d[4] = {(double)k1.x,(double)k1.y,(double)k1.z,(double)k1.w};
            #pragma unroll
            for (int i = 0; i < 4; i++) {
                double2 q01 = *(const double2*)&qd[r0+i][d];
                double2 q23 = *(const double2*)&qd[r0+i][d+2];
                // strict d-ascending per accumulator (bit-identical order)
                acc[i][0] = fma(q01.x, k0d[0], acc[i][0]);
                acc[i][0] = fma(q01.y, k0d[1], acc[i][0]);
                acc[i][0] = fma(q23.x, k0d[2], acc[i][0]);
                acc[i][0] = fma(q23.y, k0d[3], acc[i][0]);
                acc[i][1] = fma(q01.x, k1d[0], acc[i][1]);
                acc[i][1] = fma(q01.y, k1d[1], acc[i][1]);
                acc[i][1] = fma(q23.x, k1d[2], acc[i][1]);
                acc[i][1] = fma(q23.y, k1d[3], acc[i][1]);
            }
        }
        #pragma unroll
        for (int i = 0; i < 4; i++) {
            int rg = qrow_g + r0 + i;
            #pragma unroll
            for (int s01 = 0; s01 < 2; s01++) {
                int c = ktile*128 + lane + 64*s01;
                sc[i][2*ktile+s01] = (float)(acc[i][s01]*0.125 +
                                     (double)relb[(size_t)(c - rg + 511)*NHEAD + h]);
            }
        }
    }
    __syncthreads();                    // u.ks dead; u.sp may now be written

    // ---- top-32 threshold: 32 extract-max iterations, 4 rows interleaved ----
    float val[4][8];
    #pragma unroll
    for (int i = 0; i < 4; i++)
        #pragma unroll
        for (int j = 0; j < 8; j++) val[i][j] = sc[i][j];

    float rowmax[4], thresh[4];
    #pragma unroll 1
    for (int it = 0; it < TOPK; it++) {
        #pragma unroll
        for (int rr = 0; rr < 4; rr++) {
            float lm = val[rr][0];
            #pragma unroll
            for (int j = 1; j < 8; j++) lm = fmaxf(lm, val[rr][j]);
            float m = lm;
            #pragma unroll
            for (int off = 32; off >= 1; off >>= 1)
                m = fmaxf(m, __shfl_xor(m, off));
            if (it == 0) rowmax[rr] = m;
            thresh[rr] = m;
            unsigned long long ball = __ballot(lm == m);
            int first = __ffsll(ball) - 1;
            if (lane == first) {        // zap exactly one instance of m
                bool done = false;
                #pragma unroll
                for (int j = 0; j < 8; j++)
                    if (!done && val[rr][j] == m) { val[rr][j] = -__builtin_inff(); done = true; }
            }
        }
    }

    // ---- softmax weights + sparse compaction + PV + store, per row ----
    const float gate = gates[h];
    #pragma unroll
    for (int rr = 0; rr < 4; rr++) {
        int row = r0 + rr;
        float w[8];
        float sum = 0.f;
        #pragma unroll
        for (int j = 0; j < 8; j++) {
            float sv = sc[rr][j];
            float wv = (sv >= thresh[rr]) ? __expf(sv - rowmax[rr]) : 0.f;
            w[j] = wv;
            sum += wv;
        }
        #pragma unroll
        for (int off = 32; off >= 1; off >>= 1)
            sum += __shfl_xor(sum, off);
        float rscale = gate / sum;

        // compact kept entries (col ascending: j-major, lane-minor)
        int n = 0;
        #pragma unroll
        for (int j = 0; j < 8; j++) {
            bool keep = (sc[rr][j] >= thresh[rr]);
            unsigned long long mask = __ballot(keep);
            int pos = n + __popcll(mask & ((1ull << lane) - 1ull));
            if (keep && pos < 64) {
                u.sp.c[row][pos] = (unsigned short)(lane + 64*j);
                u.sp.w[row][pos] = w[j];
            }
            n += __popcll(mask);
        }
        if (n > 64) n = 64;

        // sparse PV: lane == d; entries ascending == dense k-ascending order
        float o = 0.f;
        int e = 0;
        for (; e + 4 <= n; e += 4) {
            int   c0 = u.sp.c[row][e],   c1 = u.sp.c[row][e+1];
            int   c2 = u.sp.c[row][e+2], c3 = u.sp.c[row][e+3];
            float w0 = u.sp.w[row][e],   w1 = u.sp.w[row][e+1];
            float w2 = u.sp.w[row][e+2], w3 = u.sp.w[row][e+3];
            float v0 = vbase[(size_t)c0*HDIM + lane];
            float v1 = vbase[(size_t)c1*HDIM + lane];
            float v2 = vbase[(size_t)c2*HDIM + lane];
            float v3 = vbase[(size_t)c3*HDIM + lane];
            o = fmaf(w0, v0, o);
            o = fmaf(w1, v1, o);
            o = fmaf(w2, v2, o);
            o = fmaf(w3, v3, o);
        }
        for (; e < n; e++) {
            int   c = u.sp.c[row][e];
            float wv = u.sp.w[row][e];
            o = fmaf(wv, vbase[(size_t)c*HDIM + lane], o);
        }

        aout[((size_t)(b*TTT + qrow_g + row))*EMBED + h*HDIM + lane] = o * rscale;
    }
}

// ---------------------------------------------------------------------------
extern "C" void kernel_launch(void* const* d_in, const int* in_sizes, int n_in,
                              void* d_out, int out_size, void* d_ws, size_t ws_size,
                              hipStream_t stream) {
    const float* x     = (const float*)d_in[0];
    const float* Wq    = (const float*)d_in[1];
    const float* bq    = (const float*)d_in[2];
    const float* Wk    = (const float*)d_in[3];
    const float* bk    = (const float*)d_in[4];
    const float* Wv    = (const float*)d_in[5];
    const float* bv    = (const float*)d_in[6];
    const float* Wo    = (const float*)d_in[7];
    const float* bo    = (const float*)d_in[8];
    const float* gates = (const float*)d_in[9];
    const float* relb  = (const float*)d_in[10];
    float* out = (float*)d_out;

    const size_t SZ = (size_t)BT * EMBED;   // 4,194,304 floats
    float* qb = (float*)d_ws;
    float* kb = qb + SZ;
    float* vb = kb + SZ;
    float* ab = vb + SZ;

    gemm_qk_f64<<<dim3(32,16), dim3(256), 0, stream>>>(x, Wq, bq, qb);
    gemm_qk_f64<<<dim3(32,16), dim3(256), 0, stream>>>(x, Wk, bk, kb);
    gemm_nt<<<dim3(32,8), dim3(256), 0, stream>>>(x, Wv, bv, vb, 1);
    attn_kernel<<<dim3(16,128), dim3(512), 0, stream>>>(qb, kb, vb, gates, relb, ab);
    gemm_nt<<<dim3(32,8), dim3(256), 0, stream>>>(ab, Wo, bo, out, 0);
}

// Round 6
// 1199.436 us; speedup vs baseline: 1.7673x; 1.0587x over previous
//
#include <hip/hip_runtime.h>
#include <math.h>

#define EMBED 1024
#define NHEAD 16
#define HDIM  64
#define MAXPOS 512
#define TOPK  32
#define BB    8
#define TTT   512
#define BT    (BB*TTT)   // 4096 tokens

// ---------------------------------------------------------------------------
// Q+K projection GEMM, fp64 accumulation. Round-4 body verbatim (fp32 LDS
// staging, cvt in inner loop, launch_bounds(256,2)); merged at LAUNCH level:
// blockIdx.y 0..15 -> Q (Wq,bq,outq), 16..31 -> K (Wk,bk,outk).
// Summation order identical to the passing rounds: kt, kk ascending.
// ---------------------------------------------------------------------------
__global__ __launch_bounds__(256, 2)
void gemm_qk_f64(const float* __restrict__ A,
                 const float* __restrict__ Wq, const float* __restrict__ bq_,
                 const float* __restrict__ Wk, const float* __restrict__ bk_,
                 float* __restrict__ outq, float* __restrict__ outk)
{
    __shared__ float As[16][132];
    __shared__ float Bs[16][68];
    const int t  = threadIdx.x;
    const int mb = blockIdx.x;        // 0..31  rows mb*128
    const int yy = blockIdx.y;        // 0..31
    const int nb = yy & 15;           // head
    const float* __restrict__ W    = (yy < 16) ? Wq  : Wk;
    const float* __restrict__ bias = (yy < 16) ? bq_ : bk_;
    float*                    out  = (yy < 16) ? outq : outk;
    const int tr = t >> 4, tc = t & 15;

    double acc[8][4] = {};

    for (int kt = 0; kt < 1024; kt += 16) {
        #pragma unroll
        for (int i = 0; i < 2; i++) {
            int L   = t + i * 256;
            int row = L >> 2;
            int cg  = (L & 3) * 4;
            float4 a4 = *(const float4*)&A[(size_t)(mb*128 + row)*1024 + kt + cg];
            As[cg+0][row] = a4.x; As[cg+1][row] = a4.y;
            As[cg+2][row] = a4.z; As[cg+3][row] = a4.w;
        }
        {
            int row = t >> 2, cg = (t & 3) * 4;
            float4 b4 = *(const float4*)&W[(size_t)(nb*64 + row)*1024 + kt + cg];
            Bs[cg+0][row] = b4.x; Bs[cg+1][row] = b4.y;
            Bs[cg+2][row] = b4.z; Bs[cg+3][row] = b4.w;
        }
        __syncthreads();
        #pragma unroll
        for (int kk = 0; kk < 16; kk++) {
            float a[8], bv[4];
            *(float4*)&a[0]  = *(const float4*)&As[kk][tr*8];
            *(float4*)&a[4]  = *(const float4*)&As[kk][tr*8+4];
            *(float4*)&bv[0] = *(const float4*)&Bs[kk][tc*4];
            double bd[4] = {(double)bv[0], (double)bv[1], (double)bv[2], (double)bv[3]};
            #pragma unroll
            for (int i = 0; i < 8; i++) {
                double ad = (double)a[i];
                #pragma unroll
                for (int j = 0; j < 4; j++)
                    acc[i][j] = fma(ad, bd[j], acc[i][j]);
            }
        }
        __syncthreads();
    }

    #pragma unroll
    for (int i = 0; i < 8; i++) {
        int token = mb*128 + tr*8 + i;
        int b  = token >> 9, tt = token & 511;
        int c0 = nb*64 + tc*4;
        float4 v;
        v.x = (float)(acc[i][0] + (double)bias[c0+0]);
        v.y = (float)(acc[i][1] + (double)bias[c0+1]);
        v.z = (float)(acc[i][2] + (double)bias[c0+2]);
        v.w = (float)(acc[i][3] + (double)bias[c0+3]);
        *(float4*)&out[(((size_t)b*NHEAD + nb)*TTT + tt)*HDIM + tc*4] = v;
    }
}

// ---------------------------------------------------------------------------
// fp32 GEMM (NT) for V projection (scatter=1) and O projection (scatter=0).
// Round-4 verbatim.
// ---------------------------------------------------------------------------
__global__ __launch_bounds__(256, 2)
void gemm_nt(const float* __restrict__ A, const float* __restrict__ W,
             const float* __restrict__ bias, float* __restrict__ out,
             int scatter)
{
    __shared__ float As[16][132];
    __shared__ float Bs[16][132];
    const int t  = threadIdx.x;
    const int mb = blockIdx.x;
    const int nb = blockIdx.y;
    const int tr = t >> 4, tc = t & 15;

    float acc[8][8] = {};

    for (int kt = 0; kt < 1024; kt += 16) {
        #pragma unroll
        for (int i = 0; i < 2; i++) {
            int L   = t + i * 256;
            int row = L >> 2;
            int cg  = (L & 3) * 4;
            float4 a4 = *(const float4*)&A[(size_t)(mb*128 + row)*1024 + kt + cg];
            As[cg+0][row] = a4.x; As[cg+1][row] = a4.y;
            As[cg+2][row] = a4.z; As[cg+3][row] = a4.w;
            float4 b4 = *(const float4*)&W[(size_t)(nb*128 + row)*1024 + kt + cg];
            Bs[cg+0][row] = b4.x; Bs[cg+1][row] = b4.y;
            Bs[cg+2][row] = b4.z; Bs[cg+3][row] = b4.w;
        }
        __syncthreads();
        #pragma unroll
        for (int kk = 0; kk < 16; kk++) {
            float a[8], bv[8];
            *(float4*)&a[0]  = *(const float4*)&As[kk][tr*8];
            *(float4*)&a[4]  = *(const float4*)&As[kk][tr*8+4];
            *(float4*)&bv[0] = *(const float4*)&Bs[kk][tc*8];
            *(float4*)&bv[4] = *(const float4*)&Bs[kk][tc*8+4];
            #pragma unroll
            for (int i = 0; i < 8; i++)
                #pragma unroll
                for (int j = 0; j < 8; j++)
                    acc[i][j] = fmaf(a[i], bv[j], acc[i][j]);
        }
        __syncthreads();
    }

    if (scatter) {
        #pragma unroll
        for (int i = 0; i < 8; i++) {
            int token = mb*128 + tr*8 + i;
            int b  = token >> 9, tt = token & 511;
            #pragma unroll
            for (int jg = 0; jg < 2; jg++) {
                int c = nb*128 + tc*8 + jg*4;
                int h = c >> 6, d = c & 63;
                float4 v;
                v.x = acc[i][jg*4+0] + bias[c+0];
                v.y = acc[i][jg*4+1] + bias[c+1];
                v.z = acc[i][jg*4+2] + bias[c+2];
                v.w = acc[i][jg*4+3] + bias[c+3];
                *(float4*)&out[(((size_t)b*NHEAD + h)*TTT + tt)*HDIM + d] = v;
            }
        }
    } else {
        #pragma unroll
        for (int i = 0; i < 8; i++) {
            int token = mb*128 + tr*8 + i;
            #pragma unroll
            for (int jg = 0; jg < 2; jg++) {
                int c = nb*128 + tc*8 + jg*4;
                float4 v;
                v.x = acc[i][jg*4+0] + bias[c+0];
                v.y = acc[i][jg*4+1] + bias[c+1];
                v.z = acc[i][jg*4+2] + bias[c+2];
                v.w = acc[i][jg*4+3] + bias[c+3];
                *(float4*)&out[(size_t)token*1024 + c] = v;
            }
        }
    }
}

// ---------------------------------------------------------------------------
// Attention core — round-4 body with ONE change: Q tile stored fp32 in LDS
// (q IS fp32; cvt to double on read is exact -> bit-identical fp64 dot,
// d-ascending). LDS 51.2 -> 43.5 KB so the HW fits 3 blocks/CU at runtime.
// launch_bounds kept at (512,4): no forced register cap, no spills.
// ---------------------------------------------------------------------------
__global__ __launch_bounds__(512, 4)
void attn_kernel(const float* __restrict__ qb, const float* __restrict__ kb,
                 const float* __restrict__ vb, const float* __restrict__ gates,
                 const float* __restrict__ relb, float* __restrict__ aout)
{
    __shared__ float qs[32][68];                        // 8.7 KB (padded)
    __shared__ union {
        float ks[128][68];                              // 34.8 KB  K-tile [col][d]
        struct { float w[32][64]; unsigned short c[32][64]; } sp;  // 12 KB
    } u;

    const int t    = threadIdx.x;
    const int lane = t & 63, wv = t >> 6;               // 8 waves
    const int qt   = blockIdx.x;        // 0..15
    const int bh   = blockIdx.y;        // 0..127
    const int h    = bh & 15, b = bh >> 4;
    const int qrow_g = qt * 32;
    const int r0   = wv * 4;            // this wave's 4 block-local rows

    const float* qbase = qb + ((size_t)bh*TTT + qrow_g)*HDIM;
    const float* kbase = kb + (size_t)bh*TTT*HDIM;
    const float* vbase = vb + (size_t)bh*TTT*HDIM;

    // ---- load Q tile (32x64) as fp32 ----
    {
        int row = t >> 4, cg = (t & 15) * 4;
        *(float4*)&qs[row][cg] = *(const float4*)&qbase[(size_t)row*HDIM + cg];
    }

    float sc[4][8];                     // scores: sc[i][j] = S[r0+i][lane+64j]

    // ---- scores: 4 K-tiles of 128 cols, fp64 accumulation, d ascending ----
    #pragma unroll
    for (int ktile = 0; ktile < 4; ktile++) {
        __syncthreads();                // protects u.ks (and qs on first iter)
        #pragma unroll
        for (int i = 0; i < 4; i++) {   // stage K tile as [col][d]
            int L   = t + i * 512;
            int col = L >> 4, dg = (L & 15) * 4;
            *(float4*)&u.ks[col][dg] =
                *(const float4*)&kbase[(size_t)(ktile*128 + col)*HDIM + dg];
        }
        __syncthreads();

        double acc[4][2] = {};
        #pragma unroll 2
        for (int d = 0; d < 64; d += 4) {
            float4 k0 = *(const float4*)&u.ks[lane][d];
            float4 k1 = *(const float4*)&u.ks[lane+64][d];
            double k0d[4] = {(double)k0.x,(double)k0.y,(double)k0.z,(double)k0.w};
            double k1d[4] = {(double)k1.x,(double)k1.y,(double)k1.z,(double)k1.w};
            #pragma unroll
            for (int i = 0; i < 4; i++) {
                float4 q4 = *(const float4*)&qs[r0+i][d];   // broadcast read
                double q0 = (double)q4.x, q1 = (double)q4.y;
                double q2 = (double)q4.z, q3 = (double)q4.w;
                // strict d-ascending per accumulator (bit-identical order)
                acc[i][0] = fma(q0, k0d[0], acc[i][0]);
                acc[i][0] = fma(q1, k0d[1], acc[i][0]);
                acc[i][0] = fma(q2, k0d[2], acc[i][0]);
                acc[i][0] = fma(q3, k0d[3], acc[i][0]);
                acc[i][1] = fma(q0, k1d[0], acc[i][1]);
                acc[i][1] = fma(q1, k1d[1], acc[i][1]);
                acc[i][1] = fma(q2, k1d[2], acc[i][1]);
                acc[i][1] = fma(q3, k1d[3], acc[i][1]);
            }
        }
        #pragma unroll
        for (int i = 0; i < 4; i++) {
            int rg = qrow_g + r0 + i;
            #pragma unroll
            for (int s01 = 0; s01 < 2; s01++) {
                int c = ktile*128 + lane + 64*s01;
                sc[i][2*ktile+s01] = (float)(acc[i][s01]*0.125 +
                                     (double)relb[(size_t)(c - rg + 511)*NHEAD + h]);
            }
        }
    }
    __syncthreads();                    // u.ks dead; u.sp may now be written

    // ---- top-32 threshold: 32 extract-max iterations, 4 rows interleaved ----
    float val[4][8];
    #pragma unroll
    for (int i = 0; i < 4; i++)
        #pragma unroll
        for (int j = 0; j < 8; j++) val[i][j] = sc[i][j];

    float rowmax[4], thresh[4];
    #pragma unroll 1
    for (int it = 0; it < TOPK; it++) {
        #pragma unroll
        for (int rr = 0; rr < 4; rr++) {
            float lm = val[rr][0];
            #pragma unroll
            for (int j = 1; j < 8; j++) lm = fmaxf(lm, val[rr][j]);
            float m = lm;
            #pragma unroll
            for (int off = 32; off >= 1; off >>= 1)
                m = fmaxf(m, __shfl_xor(m, off));
            if (it == 0) rowmax[rr] = m;
            thresh[rr] = m;
            unsigned long long ball = __ballot(lm == m);
            int first = __ffsll(ball) - 1;
            if (lane == first) {        // zap exactly one instance of m
                bool done = false;
                #pragma unroll
                for (int j = 0; j < 8; j++)
                    if (!done && val[rr][j] == m) { val[rr][j] = -__builtin_inff(); done = true; }
            }
        }
    }

    // ---- softmax weights + sparse compaction + PV + store, per row ----
    const float gate = gates[h];
    #pragma unroll
    for (int rr = 0; rr < 4; rr++) {
        int row = r0 + rr;
        float w[8];
        float sum = 0.f;
        #pragma unroll
        for (int j = 0; j < 8; j++) {
            float sv = sc[rr][j];
            float wv2 = (sv >= thresh[rr]) ? __expf(sv - rowmax[rr]) : 0.f;
            w[j] = wv2;
            sum += wv2;
        }
        #pragma unroll
        for (int off = 32; off >= 1; off >>= 1)
            sum += __shfl_xor(sum, off);
        float rscale = gate / sum;

        // compact kept entries (col ascending: j-major, lane-minor)
        int n = 0;
        #pragma unroll
        for (int j = 0; j < 8; j++) {
            bool keep = (sc[rr][j] >= thresh[rr]);
            unsigned long long mask = __ballot(keep);
            int pos = n + __popcll(mask & ((1ull << lane) - 1ull));
            if (keep && pos < 64) {
                u.sp.c[row][pos] = (unsigned short)(lane + 64*j);
                u.sp.w[row][pos] = w[j];
            }
            n += __popcll(mask);
        }
        if (n > 64) n = 64;

        // sparse PV: lane == d; entries ascending == dense k-ascending order
        float o = 0.f;
        int e = 0;
        for (; e + 4 <= n; e += 4) {
            int   c0 = u.sp.c[row][e],   c1 = u.sp.c[row][e+1];
            int   c2 = u.sp.c[row][e+2], c3 = u.sp.c[row][e+3];
            float w0 = u.sp.w[row][e],   w1 = u.sp.w[row][e+1];
            float w2 = u.sp.w[row][e+2], w3 = u.sp.w[row][e+3];
            float v0 = vbase[(size_t)c0*HDIM + lane];
            float v1 = vbase[(size_t)c1*HDIM + lane];
            float v2 = vbase[(size_t)c2*HDIM + lane];
            float v3 = vbase[(size_t)c3*HDIM + lane];
            o = fmaf(w0, v0, o);
            o = fmaf(w1, v1, o);
            o = fmaf(w2, v2, o);
            o = fmaf(w3, v3, o);
        }
        for (; e < n; e++) {
            int   c = u.sp.c[row][e];
            float wv2 = u.sp.w[row][e];
            o = fmaf(wv2, vbase[(size_t)c*HDIM + lane], o);
        }

        aout[((size_t)(b*TTT + qrow_g + row))*EMBED + h*HDIM + lane] = o * rscale;
    }
}

// ---------------------------------------------------------------------------
extern "C" void kernel_launch(void* const* d_in, const int* in_sizes, int n_in,
                              void* d_out, int out_size, void* d_ws, size_t ws_size,
                              hipStream_t stream) {
    const float* x     = (const float*)d_in[0];
    const float* Wq    = (const float*)d_in[1];
    const float* bq    = (const float*)d_in[2];
    const float* Wk    = (const float*)d_in[3];
    const float* bk    = (const float*)d_in[4];
    const float* Wv    = (const float*)d_in[5];
    const float* bv    = (const float*)d_in[6];
    const float* Wo    = (const float*)d_in[7];
    const float* bo    = (const float*)d_in[8];
    const float* gates = (const float*)d_in[9];
    const float* relb  = (const float*)d_in[10];
    float* out = (float*)d_out;

    const size_t SZ = (size_t)BT * EMBED;   // 4,194,304 floats
    float* qb = (float*)d_ws;
    float* kb = qb + SZ;
    float* vb = kb + SZ;
    float* ab = vb + SZ;

    gemm_qk_f64<<<dim3(32,32), dim3(256), 0, stream>>>(x, Wq, bq, Wk, bk, qb, kb);
    gemm_nt<<<dim3(32,8), dim3(256), 0, stream>>>(x, Wv, bv, vb, 1);
    attn_kernel<<<dim3(16,128), dim3(512), 0, stream>>>(qb, kb, vb, gates, relb, ab);
    gemm_nt<<<dim3(32,8), dim3(256), 0, stream>>>(ab, Wo, bo, out, 0);
}